// Round 6
// baseline (342.609 us; speedup 1.0000x reference)
//
#include <hip/hip_runtime.h>
#include <math.h>

// B=8, C=64, T=128, E=256, 4E=1024, TYPE_NUM=40, NF=128
// attn v7: t-split (grid 1024, 3 blocks/CU) MFMA K=768 -> raw scores; separate
// softmax+g+feat2 kernel. conv v3: im2col + single unified MFMA GEMM (K=1280,
// zero-padded per width) + pool. cvt and Apre-GEMM merged into one launch.

typedef __bf16 bf16x8 __attribute__((ext_vector_type(8)));
typedef float  f32x4  __attribute__((ext_vector_type(4)));

__device__ __forceinline__ float ftanh(float v) {
    float t = __expf(2.f * v);
    return 1.f - 2.f * __builtin_amdgcn_rcpf(t + 1.f);
}

__device__ __forceinline__ void gld_lds16(const __bf16* g, __bf16* l) {
    __builtin_amdgcn_global_load_lds(
        (const __attribute__((address_space(1))) void*)g,
        (__attribute__((address_space(3))) void*)l, 16, 0, 0);
}

// ---------------- megakernel: Apre fp32 GEMM (blocks 0..15) + all conversions ------
// Apre = q @ Wh[:,0:256]^T + b_hidden   (M=64,N=1024,K=256, fp32 exact)
// Whbf   [1024][1024] bf16
// Whbf_t tiled+swizzled [nc4][kc12][row256][g8], g'=kg^(row&7), cols 256+kc*64+kg*8
// Wlbf   [256][1024] bf16
// ctxbf_t tiled+swizzled [b8][ec4][t128][g8], g'=kg^(t&7)
// Wcnv   [384][1280] bf16: B[kw*128+f][e*5+i] = cw_kw[f][e][i] (i<KW else 0)
// cbc    [384] f32 concat conv biases
__global__ __launch_bounds__(256) void prep_kernel(
    const float* __restrict__ q, const float* __restrict__ Wh,
    const float* __restrict__ bh, const float* __restrict__ Wl,
    const float* __restrict__ ctx,
    const float* __restrict__ cw0, const float* __restrict__ cb0,
    const float* __restrict__ cw1, const float* __restrict__ cb1,
    const float* __restrict__ cw2, const float* __restrict__ cb2,
    float* __restrict__ Apre,
    __bf16* __restrict__ Whbf, __bf16* __restrict__ Whbf_t,
    __bf16* __restrict__ Wlbf, __bf16* __restrict__ ctxbf_t,
    __bf16* __restrict__ Wcnv, float* __restrict__ cbc)
{
    __shared__ float As[16][68];
    __shared__ float Bs[16][68];
    const int tid = threadIdx.x;
    const int bid = blockIdx.x;

    if (bid < 16) {
        // ---- Apre GEMM: m0=0, n0=bid*64, K=256 ----
        const int n0 = bid * 64;
        const int tm = tid >> 4, tn = tid & 15;
        const int lr = tid >> 2, lc = (tid & 3) * 4;
        float acc[4][4];
#pragma unroll
        for (int i = 0; i < 4; ++i)
#pragma unroll
            for (int j = 0; j < 4; ++j) acc[i][j] = 0.f;
        for (int k0 = 0; k0 < 256; k0 += 16) {
            float4 av = *reinterpret_cast<const float4*>(q + (size_t)lr * 256 + k0 + lc);
            float4 bv = *reinterpret_cast<const float4*>(Wh + (size_t)(n0 + lr) * 1024 + k0 + lc);
            As[lc + 0][lr] = av.x; As[lc + 1][lr] = av.y; As[lc + 2][lr] = av.z; As[lc + 3][lr] = av.w;
            Bs[lc + 0][lr] = bv.x; Bs[lc + 1][lr] = bv.y; Bs[lc + 2][lr] = bv.z; Bs[lc + 3][lr] = bv.w;
            __syncthreads();
#pragma unroll
            for (int kk = 0; kk < 16; ++kk) {
                float4 a = *reinterpret_cast<const float4*>(&As[kk][tm * 4]);
                float4 b = *reinterpret_cast<const float4*>(&Bs[kk][tn * 4]);
                float ar[4] = {a.x, a.y, a.z, a.w};
                float br[4] = {b.x, b.y, b.z, b.w};
#pragma unroll
                for (int i = 0; i < 4; ++i)
#pragma unroll
                    for (int j = 0; j < 4; ++j) acc[i][j] += ar[i] * br[j];
            }
            __syncthreads();
        }
#pragma unroll
        for (int i = 0; i < 4; ++i) {
            int m = tm * 4 + i;
            float4 o;
            o.x = acc[i][0] + bh[n0 + tn * 4 + 0];
            o.y = acc[i][1] + bh[n0 + tn * 4 + 1];
            o.z = acc[i][2] + bh[n0 + tn * 4 + 2];
            o.w = acc[i][3] + bh[n0 + tn * 4 + 3];
            *reinterpret_cast<float4*>(Apre + (size_t)m * 1024 + n0 + tn * 4) = o;
        }
        return;
    }

    int idx = (bid - 16) * 256 + tid;            // < 1933696
    if (idx >= 1933696) return;
    if (idx < 1048576) { Whbf[idx] = (__bf16)Wh[idx]; return; }
    if (idx < 1146880) {                          // Whbf_t granules
        int di = idx - 1048576;
        int nc = di / 24576, rem = di - nc * 24576;
        int kc = rem >> 11, row = (rem >> 3) & 255, kgp = rem & 7;
        int kg = kgp ^ (row & 7);
        const float* s = Wh + (size_t)(nc * 256 + row) * 1024 + 256 + kc * 64 + kg * 8;
        bf16x8 u;
#pragma unroll
        for (int i = 0; i < 8; ++i) u[i] = (__bf16)s[i];
        *reinterpret_cast<bf16x8*>(Whbf_t + (size_t)di * 8) = u;
        return;
    }
    if (idx < 1409024) { int j = idx - 1146880; Wlbf[j] = (__bf16)Wl[j]; return; }
    if (idx < 1441792) {                          // ctxbf_t granules
        int di = idx - 1409024;
        int b = di >> 12, ec = (di >> 10) & 3, t = (di >> 3) & 127, kgp = di & 7;
        int kg = kgp ^ (t & 7);
        const float* s = ctx + (size_t)(b * 128 + t) * 256 + ec * 64 + kg * 8;
        bf16x8 u;
#pragma unroll
        for (int i = 0; i < 8; ++i) u[i] = (__bf16)s[i];
        *reinterpret_cast<bf16x8*>(ctxbf_t + (size_t)di * 8) = u;
        return;
    }
    if (idx < 1933312) {                          // Wcnv
        int j = idx - 1441792;
        int f1 = j / 1280, k = j - f1 * 1280;
        int e = k / 5, i = k - e * 5;
        int kw = f1 >> 7, f = f1 & 127;
        int KW = 5 - kw;
        float v = 0.f;
        if (i < KW) {
            const float* cw = (kw == 0) ? cw0 : (kw == 1) ? cw1 : cw2;
            v = cw[(size_t)(f * 256 + e) * KW + i];
        }
        Wcnv[j] = (__bf16)v;
        return;
    }
    {                                             // cbc
        int j = idx - 1933312;
        int kw = j >> 7, f = j & 127;
        cbc[j] = (kw == 0 ? cb0 : kw == 1 ? cb1 : cb2)[f];
    }
}

// ---------------- attn_mm: t-split bf16-MFMA K=768 -> raw scores ----------------
// grid 1024: bid = (b*64+c)*2 + th. Block tile 64t x 1024j (4 nc of 256).
// 4 waves: w0 = t-half(32), w1 = j-half(128). acc 2x8 frags.
__global__ __launch_bounds__(256, 3) void attn_mm_kernel(
    const float* __restrict__ q,        // [64][256]
    const float* __restrict__ ctx,      // [8][128][256] fp32
    const __bf16* __restrict__ ctxbf_t,
    const __bf16* __restrict__ Whbf_t,
    const float* __restrict__ Wv,       // [1024]
    const float* __restrict__ Apre,     // [64][1024]
    float* __restrict__ scG)            // [512][128] raw scores (no bv/mask)
{
    __shared__ __bf16 Us[64 * 64];
    __shared__ __bf16 Ws[256 * 64];
    __shared__ float qc[256];
    __shared__ float sc[64];

    const int tid = threadIdx.x;
    const int bid = blockIdx.x;
    const int b = bid >> 7, c = (bid >> 1) & 63, th = bid & 1;
    const int wave = tid >> 6, lane = tid & 63;
    const int w0 = wave >> 1, w1 = wave & 1;
    const int m0 = w0 * 32;
    const int l15 = lane & 15, quad = lane >> 4;
    const int swz = l15 & 7;

    qc[tid] = q[c * 256 + tid];
    if (tid < 64) sc[tid] = 0.f;
    __syncthreads();

    for (int nc = 0; nc < 4; ++nc) {
        f32x4 acc[2][8];
#pragma unroll
        for (int mi = 0; mi < 2; ++mi)
#pragma unroll
            for (int ni = 0; ni < 8; ++ni) acc[mi][ni] = (f32x4){0.f, 0.f, 0.f, 0.f};

        for (int kc = 0; kc < 12; ++kc) {
            __syncthreads();
            // W tile: 2048 granules async, 512/wave
            const __bf16* wtile = Whbf_t + (size_t)(nc * 12 + kc) * 16384;
#pragma unroll
            for (int it = 0; it < 8; ++it) {
                int gidx = wave * 512 + it * 64;
                gld_lds16(wtile + (size_t)(gidx + lane) * 8, &Ws[gidx * 8]);
            }
            const int region = kc >> 2, ec = kc & 3;
            if (region == 0) {
                // U tile: 512 granules async (this th-half), 128/wave
                const __bf16* ctile = ctxbf_t + (size_t)(b * 4 + ec) * 8192 + th * 4096;
#pragma unroll
                for (int it = 0; it < 2; ++it) {
                    int gidx = wave * 128 + it * 64;
                    gld_lds16(ctile + (size_t)(gidx + lane) * 8, &Us[gidx * 8]);
                }
            } else {
                const bool isabs = (region == 1);
                const int e0 = ec * 64;
#pragma unroll
                for (int it = 0; it < 2; ++it) {
                    int idx = tid + it * 256;      // 512 granules
                    int t = idx >> 3, kg = idx & 7;
                    int eb = e0 + kg * 8;
                    const float* cp = ctx + (size_t)(b * 128 + th * 64 + t) * 256 + eb;
                    float4 c0 = *reinterpret_cast<const float4*>(cp);
                    float4 c1 = *reinterpret_cast<const float4*>(cp + 4);
                    float cv[8] = {c0.x, c0.y, c0.z, c0.w, c1.x, c1.y, c1.z, c1.w};
                    bf16x8 u;
#pragma unroll
                    for (int i = 0; i < 8; ++i) {
                        float qv = qc[eb + i];
                        float x = isabs ? fabsf(qv - cv[i]) : qv * cv[i];
                        u[i] = (__bf16)x;
                    }
                    *reinterpret_cast<bf16x8*>(&Us[t * 64 + (kg ^ (t & 7)) * 8]) = u;
                }
            }
            __syncthreads();
#pragma unroll
            for (int ks = 0; ks < 2; ++ks) {
                const int c8 = (((ks * 4 + quad) ^ swz)) * 8;
                bf16x8 a[2], bf[8];
#pragma unroll
                for (int mi = 0; mi < 2; ++mi)
                    a[mi] = *reinterpret_cast<const bf16x8*>(
                        &Us[(m0 + mi * 16 + l15) * 64 + c8]);
#pragma unroll
                for (int ni = 0; ni < 8; ++ni)
                    bf[ni] = *reinterpret_cast<const bf16x8*>(
                        &Ws[(w1 * 128 + ni * 16 + l15) * 64 + c8]);
#pragma unroll
                for (int mi = 0; mi < 2; ++mi)
#pragma unroll
                    for (int ni = 0; ni < 8; ++ni)
                        acc[mi][ni] = __builtin_amdgcn_mfma_f32_16x16x32_bf16(
                            a[mi], bf[ni], acc[mi][ni], 0, 0, 0);
            }
        }

        // epilogue: tanh + Wv partial dot
        const int jcol = nc * 256 + w1 * 128 + l15;
        float av[8], wv[8];
#pragma unroll
        for (int ni = 0; ni < 8; ++ni) {
            av[ni] = Apre[c * 1024 + jcol + ni * 16];
            wv[ni] = Wv[jcol + ni * 16];
        }
#pragma unroll
        for (int mi = 0; mi < 2; ++mi) {
            const int tbase = m0 + mi * 16 + quad * 4;
            float p[4];
#pragma unroll
            for (int r = 0; r < 4; ++r) {
                float s = 0.f;
#pragma unroll
                for (int ni = 0; ni < 8; ++ni)
                    s += ftanh(acc[mi][ni][r] + av[ni]) * wv[ni];
                p[r] = s;
            }
#pragma unroll
            for (int off = 1; off < 16; off <<= 1)
#pragma unroll
                for (int r = 0; r < 4; ++r) p[r] += __shfl_xor(p[r], off, 16);
            if (l15 == 0) {
#pragma unroll
                for (int r = 0; r < 4; ++r) atomicAdd(&sc[tbase + r], p[r]);
            }
        }
        __syncthreads();
    }

    if (tid < 64) scG[(size_t)(bid >> 1) * 128 + th * 64 + tid] = sc[tid];
}

// ---------------- attn_fin: mask + softmax + g + feat2 ----------------
__global__ __launch_bounds__(256) void attn_fin_kernel(
    const float* __restrict__ q, const float* __restrict__ ctx,
    const int* __restrict__ mask, const float* __restrict__ bv,
    const float* __restrict__ scG, __bf16* __restrict__ feat2)
{
    __shared__ float sc[128];
    __shared__ float red;
    const int tid = threadIdx.x;
    const int bc = blockIdx.x, b = bc >> 6, c = bc & 63;

    if (tid < 128) {
        float s = scG[(size_t)bc * 128 + tid] + bv[0];
        if (mask[b * 128 + tid] < 1) s = -1e10f;
        sc[tid] = s;
    }
    __syncthreads();
    if (tid < 64) {
        float m = fmaxf(sc[tid], sc[tid + 64]);
        for (int off = 32; off; off >>= 1) m = fmaxf(m, __shfl_xor(m, off, 64));
        if (tid == 0) red = m;
    }
    __syncthreads();
    const float mx = red;
    if (tid < 128) sc[tid] = __expf(sc[tid] - mx);
    __syncthreads();
    if (tid < 64) {
        float s = sc[tid] + sc[tid + 64];
        for (int off = 32; off; off >>= 1) s += __shfl_xor(s, off, 64);
        if (tid == 0) red = s;
    }
    __syncthreads();
    const float inv = 1.f / red;

    float gv = 0.f;
    for (int t = 0; t < 128; ++t) gv += sc[t] * ctx[(size_t)(b * 128 + t) * 256 + tid];
    gv *= inv;
    float qv = q[c * 256 + tid];
    __bf16* o = feat2 + (size_t)bc * 768 + tid;
    o[0]   = (__bf16)gv;
    o[256] = (__bf16)fabsf(qv - gv);
    o[512] = (__bf16)(qv * gv);
}

// ---------------- bf16 MFMA GEMM: C = act(A @ B^T + bias), 64x64 tile ----------------
// BMODE 0: bias[col]; BMODE 1: bias[(row&63)*1024 + col]
template <int ACT, int OUTBF, int BMODE>
__global__ __launch_bounds__(256) void mfma_gemm_kernel(
    const __bf16* __restrict__ A, int lda,
    const __bf16* __restrict__ B, int ldb,
    const float* __restrict__ bias, void* __restrict__ Cout,
    int K, int ldc)
{
    __shared__ __bf16 As[64 * 72];
    __shared__ __bf16 Bs[64 * 72];
    const int tid = threadIdx.x;
    const int wave = tid >> 6, lane = tid & 63;
    const int w0 = wave >> 1, w1 = wave & 1;
    const int l15 = lane & 15, quad = lane >> 4;
    const int m0 = blockIdx.y * 64, n0 = blockIdx.x * 64;

    f32x4 acc[2][2];
#pragma unroll
    for (int mi = 0; mi < 2; ++mi)
#pragma unroll
        for (int ni = 0; ni < 2; ++ni) acc[mi][ni] = (f32x4){0.f, 0.f, 0.f, 0.f};

    for (int k0 = 0; k0 < K; k0 += 64) {
        __syncthreads();
#pragma unroll
        for (int it = 0; it < 2; ++it) {
            int idx = tid + it * 256;
            int row = idx >> 3, kg = idx & 7;
            int4 va = *reinterpret_cast<const int4*>(A + (size_t)(m0 + row) * lda + k0 + kg * 8);
            *reinterpret_cast<int4*>(&As[row * 72 + kg * 8]) = va;
            int4 vb = *reinterpret_cast<const int4*>(B + (size_t)(n0 + row) * ldb + k0 + kg * 8);
            *reinterpret_cast<int4*>(&Bs[row * 72 + kg * 8]) = vb;
        }
        __syncthreads();
#pragma unroll
        for (int ks = 0; ks < 2; ++ks) {
            bf16x8 a[2], bb[2];
#pragma unroll
            for (int mi = 0; mi < 2; ++mi)
                a[mi] = *reinterpret_cast<const bf16x8*>(
                    &As[(w0 * 32 + mi * 16 + l15) * 72 + ks * 32 + quad * 8]);
#pragma unroll
            for (int ni = 0; ni < 2; ++ni)
                bb[ni] = *reinterpret_cast<const bf16x8*>(
                    &Bs[(w1 * 32 + ni * 16 + l15) * 72 + ks * 32 + quad * 8]);
#pragma unroll
            for (int mi = 0; mi < 2; ++mi)
#pragma unroll
                for (int ni = 0; ni < 2; ++ni)
                    acc[mi][ni] = __builtin_amdgcn_mfma_f32_16x16x32_bf16(
                        a[mi], bb[ni], acc[mi][ni], 0, 0, 0);
        }
    }

#pragma unroll
    for (int mi = 0; mi < 2; ++mi)
#pragma unroll
        for (int ni = 0; ni < 2; ++ni) {
            int col = n0 + w1 * 32 + ni * 16 + l15;
#pragma unroll
            for (int r = 0; r < 4; ++r) {
                int row = m0 + w0 * 32 + mi * 16 + quad * 4 + r;
                float bsv = (BMODE == 0) ? bias[col] : bias[(row & 63) * 1024 + col];
                float v = acc[mi][ni][r] + bsv;
                if (ACT) v = ftanh(v);
                if (OUTBF) ((__bf16*)Cout)[(size_t)row * ldc + col] = (__bf16)v;
                else       ((float*)Cout)[(size_t)row * ldc + col] = v;
            }
        }
}

// ---------------- im2col: A[(b,p)][e*5+i] = xb[b][p+i][e] (0 if p+i>63) -----------
__global__ void im2col_kernel(const __bf16* __restrict__ xb, __bf16* __restrict__ Aim)
{
    int idx = blockIdx.x * 256 + threadIdx.x;    // < 655360
    int row = idx / 1280, k = idx - row * 1280;
    int e = k / 5, i = k - e * 5;
    int b = row >> 6, p = row & 63;
    __bf16 v = (__bf16)0.f;
    if (p + i < 64) v = xb[(size_t)(b * 64 + p + i) * 256 + e];
    Aim[idx] = v;
}

// ---------------- pool: relu + max over valid positions ----------------
__global__ __launch_bounds__(128) void pool_kernel(
    const float* __restrict__ y, float* __restrict__ cnn)
{
    const int bi = blockIdx.x;                   // kw*8 + b
    const int kw = bi >> 3, b = bi & 7;
    const int f = threadIdx.x;
    const int KW = 5 - kw, P = 64 - KW + 1;
    float mx = 0.f;
    for (int p = 0; p < P; ++p)
        mx = fmaxf(mx, y[(size_t)(b * 64 + p) * 384 + kw * 128 + f]);
    cnn[b * 384 + kw * 128 + f] = mx;            // relu folded: floor 0
}

// ---------------- final FC: 320 blocks x 64 threads, wave reduce ----------------
__global__ __launch_bounds__(64) void final_kernel(
    const float* __restrict__ cnn, const float* __restrict__ Wc,
    const float* __restrict__ bc, float* __restrict__ out)
{
    const int o = blockIdx.x;                    // b*40 + t
    const int b = o / 40, t = o - b * 40;
    const int lane = threadIdx.x;
    float s = 0.f;
#pragma unroll
    for (int k = 0; k < 6; ++k)
        s += cnn[b * 384 + lane + k * 64] * Wc[(size_t)t * 384 + lane + k * 64];
    for (int off = 32; off; off >>= 1) s += __shfl_xor(s, off);
    if (lane == 0) out[o] = s + bc[t];
}

extern "C" void kernel_launch(void* const* d_in, const int* in_sizes, int n_in,
                              void* d_out, int out_size, void* d_ws, size_t ws_size,
                              hipStream_t stream)
{
    (void)in_sizes; (void)n_in; (void)out_size; (void)ws_size;
    const float* q    = (const float*)d_in[0];
    const float* ctx  = (const float*)d_in[1];
    const int*   mask = (const int*)d_in[2];
    const float* Wh   = (const float*)d_in[3];
    const float* bh   = (const float*)d_in[4];
    const float* Wv   = (const float*)d_in[5];
    const float* bv   = (const float*)d_in[6];
    const float* Wl   = (const float*)d_in[7];
    const float* bl   = (const float*)d_in[8];
    const float* cw0  = (const float*)d_in[9];
    const float* cb0  = (const float*)d_in[10];
    const float* cw1  = (const float*)d_in[11];
    const float* cb1  = (const float*)d_in[12];
    const float* cw2  = (const float*)d_in[13];
    const float* cb2  = (const float*)d_in[14];
    const float* Wc   = (const float*)d_in[15];
    const float* bc   = (const float*)d_in[16];

    float* ws   = (float*)d_ws;
    float* Apre = ws;                     // 65536
    float* scG  = Apre + 65536;           // 65536
    float* cnn  = scG + 65536;            // 3072
    float* y    = cnn + 3072;             // 196608 (512*384)
    float* cbc  = y + 196608;             // 384
    __bf16* bfb    = (__bf16*)(cbc + 384);
    __bf16* Whbf   = bfb;                 // 1048576
    __bf16* Whbf_t = Whbf   + 1048576;    // 786432
    __bf16* ctxbf_t= Whbf_t + 786432;     // 262144
    __bf16* Wlbf   = ctxbf_t+ 262144;     // 262144
    __bf16* feat2b = Wlbf   + 262144;     // 393216 (512*768)
    __bf16* h2b    = feat2b + 393216;     // 524288
    __bf16* xb     = h2b    + 524288;     // 131072 (512*256)
    __bf16* Aim    = xb     + 131072;     // 655360 (512*1280)
    __bf16* Wcnv   = Aim    + 655360;     // 491520 (384*1280)
    // total ~10.4 MB of d_ws

    dim3 blk(256);
    // prep: Apre GEMM (16 blocks) + all conversions
    prep_kernel<<<7570, blk, 0, stream>>>(q, Wh, bh, Wl, ctx, cw0, cb0, cw1, cb1,
                                          cw2, cb2, Apre, Whbf, Whbf_t, Wlbf,
                                          ctxbf_t, Wcnv, cbc);
    // attn matmul (t-split) -> raw scores; then softmax + g + feat2
    attn_mm_kernel<<<1024, blk, 0, stream>>>(q, ctx, ctxbf_t, Whbf_t, Wv, Apre, scG);
    attn_fin_kernel<<<512, blk, 0, stream>>>(q, ctx, mask, bv, scG, feat2b);
    // h2 = tanh(feat2 @ Wh[:,256:]^T + Apre[c]); x = h2 @ Wl^T + bl (bf16 out)
    mfma_gemm_kernel<1, 1, 1><<<dim3(16, 8), blk, 0, stream>>>(
        feat2b, 768, Whbf + 256, 1024, Apre, h2b, 768, 1024);
    mfma_gemm_kernel<0, 1, 0><<<dim3(4, 8), blk, 0, stream>>>(
        h2b, 1024, Wlbf, 1024, bl, xb, 1024, 256);
    // conv: im2col + unified MFMA GEMM (K=1280) + pool
    im2col_kernel<<<2560, blk, 0, stream>>>(xb, Aim);
    mfma_gemm_kernel<0, 0, 0><<<dim3(6, 8), blk, 0, stream>>>(
        Aim, 1280, Wcnv, 1280, cbc, y, 1280, 384);
    pool_kernel<<<24, 128, 0, stream>>>(y, cnn);
    final_kernel<<<320, 64, 0, stream>>>(cnn, Wc, bc, (float*)d_out);
}